// Round 6
// baseline (111.737 us; speedup 1.0000x reference)
//
#include <hip/hip_runtime.h>

// Problem: T=4096, C=64, D=512.
// out[t,c,d] = exp(rowsum(W)[c] * colsum(W)[d]) / D   (independent of t and x)
//
// Fused single kernel. R5 found the write-concurrency sweet spot region:
// 8 blocks/CU -> 4.5 TB/s, 1 block/CU -> 5.8 TB/s effective. This probe: 2
// blocks/CU (512 x 256) so one block's store stream hides the other block's
// prologue (w reduction) and tail drain. Stride (131072 float4 = 2 MB) is a
// multiple of the remap tile (8192 float4), so each thread's source value is
// loop-invariant.

#define T_DIM 4096
#define C_DIM 64
#define D_DIM 512

typedef float f32x4 __attribute__((ext_vector_type(4)));

__global__ __launch_bounds__(256) void fused_broadcast_kernel(
    const float* __restrict__ w, f32x4* __restrict__ out) {
    const int t = threadIdx.x;              // 0..255
    const unsigned b = blockIdx.x;          // 0..511
    const unsigned tid = b * 256u + t;      // 0..131071

    // ---- which remap entries does this thread store? ----
    // source float4 index = tid & 8191; c = (tid>>7) & 63 = (b&31)*2 + (t>>7);
    // d-group dbase = (4t) & 511 (independent of b).
    const int c0 = (int)((b & 31u) * 2u);   // rows covered by this block
    const int c1 = c0 + 1;
    const int dbase = (4 * t) & (D_DIM - 1);

    // ---- row sums rs[c0], rs[c1]: block reduce over 512 floats each ----
    float p0 = w[c0 * D_DIM + t] + w[c0 * D_DIM + 256 + t];
    float p1 = w[c1 * D_DIM + t] + w[c1 * D_DIM + 256 + t];
    #pragma unroll
    for (int off = 32; off > 0; off >>= 1) {
        p0 += __shfl_down(p0, off);
        p1 += __shfl_down(p1, off);
    }
    __shared__ float red[8];                // 4 waves x 2 rows
    const int wave = t >> 6, lane = t & 63;
    if (lane == 0) { red[wave * 2] = p0; red[wave * 2 + 1] = p1; }
    __syncthreads();
    const float rs0 = (red[0] + red[2]) + (red[4] + red[6]);
    const float rs1 = (red[1] + red[3]) + (red[5] + red[7]);
    const float rs = (t >> 7) ? rs1 : rs0;

    // ---- col sums cs[dbase..dbase+3]: 64 coalesced f32x4 loads (L2-hot) ----
    const f32x4* col = (const f32x4*)(w + dbase);   // row stride = 128 f32x4
    f32x4 a0 = {0.f, 0.f, 0.f, 0.f}, a1 = a0, a2 = a0, a3 = a0;
    #pragma unroll
    for (int r = 0; r < C_DIM; r += 4) {
        a0 += col[(r + 0) * (D_DIM / 4)];
        a1 += col[(r + 1) * (D_DIM / 4)];
        a2 += col[(r + 2) * (D_DIM / 4)];
        a3 += col[(r + 3) * (D_DIM / 4)];
    }
    const f32x4 cs4 = (a0 + a1) + (a2 + a3);

    // ---- remap value (det = D for zero input colsums) ----
    const float inv_det = 1.0f / (float)D_DIM;
    f32x4 v;
    v.x = expf(rs * cs4.x) * inv_det;
    v.y = expf(rs * cs4.y) * inv_det;
    v.z = expf(rs * cs4.z) * inv_det;
    v.w = expf(rs * cs4.w) * inv_det;

    // ---- stream 256 NT stores, 2 MB grid stride ----
    const unsigned STRIDE = 512u * 256u;     // 131072 float4 = mult of 8192
    const int ITERS = (T_DIM * C_DIM * D_DIM / 4) / STRIDE;  // 256
    f32x4* p = out + tid;
    #pragma unroll 8
    for (int i = 0; i < ITERS; ++i) {
        __builtin_nontemporal_store(v, p);
        p += STRIDE;
    }
}

extern "C" void kernel_launch(void* const* d_in, const int* in_sizes, int n_in,
                              void* d_out, int out_size, void* d_ws, size_t ws_size,
                              hipStream_t stream) {
    // d_in[0] = x (unused by the math), d_in[1] = weight (64 x 512 f32)
    const float* weight = (const float*)d_in[1];
    fused_broadcast_kernel<<<512, 256, 0, stream>>>(weight, (f32x4*)d_out);
}

// Round 7
// 98.792 us; speedup vs baseline: 1.1310x; 1.1310x over previous
//
#include <hip/hip_runtime.h>

// Problem: T=4096, C=64, D=512.
// out[t,c,d] = exp(rowsum(W)[c] * colsum(W)[d]) / D   (independent of t and x)
//
// Fused single kernel, winning R5 geometry: 256 blocks x 256 threads
// (1 block/CU, 4 waves/CU), each thread streams 512 float4 stores at 1 MB
// grid stride. Concurrency curve measured: 1 blk/CU=97us, 2=112, 8=129 ->
// low stream count wins. This round's single variable: REGULAR stores
// instead of non-temporal, mimicking rocclr fillBuffer (6.6-6.8 TB/s) --
// write-allocate + L2 writeback drains as batched full-line writes.

#define T_DIM 4096
#define C_DIM 64
#define D_DIM 512

typedef float f32x4 __attribute__((ext_vector_type(4)));

__global__ __launch_bounds__(256) void fused_broadcast_kernel(
    const float* __restrict__ w, f32x4* __restrict__ out) {
    const int t = threadIdx.x;              // 0..255
    const unsigned b = blockIdx.x;          // 0..255
    const unsigned tid = b * 256u + t;      // 0..65535

    // ---- which remap entries does this thread store? ----
    // source float4 index = tid & 8191; c = (tid>>7) & 63 = (b&31)*2 + (t>>7);
    // d-group dbase = (4t) & 511 (independent of b).
    const int c0 = (int)((b & 31u) * 2u);   // rows covered by this block
    const int c1 = c0 + 1;
    const int dbase = (4 * t) & (D_DIM - 1);

    // ---- row sums rs[c0], rs[c1]: block reduce over 512 floats each ----
    float p0 = w[c0 * D_DIM + t] + w[c0 * D_DIM + 256 + t];
    float p1 = w[c1 * D_DIM + t] + w[c1 * D_DIM + 256 + t];
    #pragma unroll
    for (int off = 32; off > 0; off >>= 1) {
        p0 += __shfl_down(p0, off);
        p1 += __shfl_down(p1, off);
    }
    __shared__ float red[8];                // 4 waves x 2 rows
    const int wave = t >> 6, lane = t & 63;
    if (lane == 0) { red[wave * 2] = p0; red[wave * 2 + 1] = p1; }
    __syncthreads();
    const float rs0 = (red[0] + red[2]) + (red[4] + red[6]);
    const float rs1 = (red[1] + red[3]) + (red[5] + red[7]);
    const float rs = (t >> 7) ? rs1 : rs0;

    // ---- col sums cs[dbase..dbase+3]: 64 coalesced f32x4 loads (L2-hot) ----
    const f32x4* col = (const f32x4*)(w + dbase);   // row stride = 128 f32x4
    f32x4 a0 = {0.f, 0.f, 0.f, 0.f}, a1 = a0, a2 = a0, a3 = a0;
    #pragma unroll
    for (int r = 0; r < C_DIM; r += 4) {
        a0 += col[(r + 0) * (D_DIM / 4)];
        a1 += col[(r + 1) * (D_DIM / 4)];
        a2 += col[(r + 2) * (D_DIM / 4)];
        a3 += col[(r + 3) * (D_DIM / 4)];
    }
    const f32x4 cs4 = (a0 + a1) + (a2 + a3);

    // ---- remap value (det = D for zero input colsums) ----
    const float inv_det = 1.0f / (float)D_DIM;
    f32x4 v;
    v.x = expf(rs * cs4.x) * inv_det;
    v.y = expf(rs * cs4.y) * inv_det;
    v.z = expf(rs * cs4.z) * inv_det;
    v.w = expf(rs * cs4.w) * inv_det;

    // ---- stream 512 regular stores, 1 MB grid stride ----
    const unsigned STRIDE = 256u * 256u;     // 65536 float4 = mult of 8192
    const int ITERS = (T_DIM * C_DIM * D_DIM / 4) / STRIDE;  // 512
    f32x4* p = out + tid;
    #pragma unroll 4
    for (int i = 0; i < ITERS; ++i) {
        *p = v;
        p += STRIDE;
    }
}

extern "C" void kernel_launch(void* const* d_in, const int* in_sizes, int n_in,
                              void* d_out, int out_size, void* d_ws, size_t ws_size,
                              hipStream_t stream) {
    // d_in[0] = x (unused by the math), d_in[1] = weight (64 x 512 f32)
    const float* weight = (const float*)d_in[1];
    fused_broadcast_kernel<<<256, 256, 0, stream>>>(weight, (f32x4*)d_out);
}